// Round 1
// baseline (1234.001 us; speedup 1.0000x reference)
//
#include <hip/hip_runtime.h>
#include <stdint.h>
#include <stddef.h>

// Problem constants
#define BSZ 64
#define MM  2048
#define DD  1024
#define HH  1024
#define RR  (BSZ * MM)   // 131072 rows of the big GEMM

typedef float  float4v  __attribute__((ext_vector_type(4)));
typedef float  float8v  __attribute__((ext_vector_type(8)));
typedef short  short4v  __attribute__((ext_vector_type(4)));
typedef short  short8v  __attribute__((ext_vector_type(8)));
typedef __bf16 bf16x4v  __attribute__((ext_vector_type(4)));
typedef __bf16 bf16x8v  __attribute__((ext_vector_type(8)));

__device__ __forceinline__ short8v cvt_f32x8_bf16(float4v lo, float4v hi) {
    float8v f;
    f[0] = lo[0]; f[1] = lo[1]; f[2] = lo[2]; f[3] = lo[3];
    f[4] = hi[0]; f[5] = hi[1]; f[6] = hi[2]; f[7] = hi[3];
    union { bf16x8v b; short8v s; } u;
    u.b = __builtin_convertvector(f, bf16x8v);   // v_cvt_pk_bf16_f32 x4
    return u.s;
}

// tanh(x) = sign(x) * (1 - 2e/(1+e)), e = exp(-2|x|). No overflow, ~6 VALU ops.
__device__ __forceinline__ float fast_tanh(float x) {
    float ax = __builtin_fabsf(x);
    float e  = __builtin_amdgcn_exp2f(ax * -2.88539008177792681f); // e^{-2ax}
    float r  = __builtin_amdgcn_rcpf(1.0f + e);
    float t  = __builtin_fmaf(-2.0f * e, r, 1.0f);
    return __builtin_copysignf(t, x);
}

// ---------------------------------------------------------------- cast Wm -> bf16
__global__ __launch_bounds__(256) void cast_wm_kernel(const float* __restrict__ wm,
                                                      short* __restrict__ out) {
    int i = (blockIdx.x * 256 + threadIdx.x) * 4;
    float4v f = *(const float4v*)(wm + i);
    union { bf16x4v b; short4v s; } u;
    u.b = __builtin_convertvector(f, bf16x4v);
    *(short4v*)(out + i) = u.s;
}

// ---------------------------------------------------------------- qproj (fp32 exact)
// qproj[b,h] = sum_d query[b,d]*Wq[h,d] + bq[h]
__global__ __launch_bounds__(256) void qproj_kernel(const float* __restrict__ query,
                                                    const float* __restrict__ Wq,
                                                    const float* __restrict__ bq,
                                                    float* __restrict__ qproj) {
    __shared__ __align__(16) float qs[DD];
    const int b = blockIdx.y;
    const int h = blockIdx.x * 256 + threadIdx.x;
    for (int i = threadIdx.x; i < DD; i += 256) qs[i] = query[b * DD + i];
    __syncthreads();
    const float4v* wrow = (const float4v*)(Wq + (size_t)h * DD);
    float acc = 0.0f;
#pragma unroll 4
    for (int d4 = 0; d4 < DD / 4; ++d4) {
        float4v w = wrow[d4];
        float4v q = *(const float4v*)(qs + d4 * 4);
        acc += w[0] * q[0] + w[1] * q[1] + w[2] * q[2] + w[3] * q[3];
    }
    qproj[b * HH + h] = acc + bq[h];
}

// ---------------------------------------------------------------- big fused GEMM
// attn[r] += sum_h tanh( (memory @ Wm^T)[r,h] + qproj[b,h] ) * v[h]
// 128x128 tile, BK=32, 4 waves (2x2), each wave 4x4 frags of 16x16x32 bf16 MFMA.
// A (memory) staged fp32 via global_load_lds; converted to bf16 at frag read.
__global__ __launch_bounds__(256) void gemm_attn_kernel(
    const float* __restrict__ memf, const short* __restrict__ wmbf,
    const float* __restrict__ qproj, const float* __restrict__ vvec,
    float* __restrict__ attn) {
    __shared__ __align__(16) float As[128 * 32];   // 16 KB fp32 [m][k]
    __shared__ __align__(16) short Bs[128 * 32];   // 8 KB bf16 [n][k]

    const int tid  = threadIdx.x;
    const int lane = tid & 63;
    const int wave = tid >> 6;
    const int wx = wave & 1, wy = wave >> 1;

    // XCD-aware swizzle: the 8 column-tiles of one row-tile land on one XCD
    // so the 512 KB A row-tile is served from that XCD's L2 after first touch.
    const int bi    = blockIdx.x;
    const int xcd   = bi & 7;
    const int idx   = bi >> 3;
    const int tileR = xcd * 128 + (idx >> 3);   // 0..1023
    const int tileC = idx & 7;                  // 0..7
    const int r0 = tileR * 128;
    const int h0 = tileC * 128;

    // Staging source pointers (global side is per-lane; LDS side uniform+lane*16)
    const float* aptr[4];
#pragma unroll
    for (int j = 0; j < 4; ++j) {
        int i   = wave * 4 + j;
        int row = i * 8 + (lane >> 3);
        int col = (lane & 7) * 4;
        aptr[j] = memf + (size_t)(r0 + row) * DD + col;
    }
    const short* bptr[2];
#pragma unroll
    for (int j = 0; j < 2; ++j) {
        int i   = wave * 2 + j;
        int row = i * 16 + (lane >> 2);
        int col = (lane & 3) * 8;
        bptr[j] = wmbf + (size_t)(h0 + row) * DD + col;
    }

    float4v acc[4][4];
#pragma unroll
    for (int a = 0; a < 4; ++a)
#pragma unroll
        for (int b = 0; b < 4; ++b) acc[a][b] = (float4v)0.0f;

    const int c  = lane & 15;
    const int g  = lane >> 4;
    const int k8 = g * 8;

    for (int kt = 0; kt < DD / 32; ++kt) {
        __syncthreads();
#pragma unroll
        for (int j = 0; j < 4; ++j) {
            __builtin_amdgcn_global_load_lds(
                (const __attribute__((address_space(1))) void*)(aptr[j]),
                (__attribute__((address_space(3))) void*)((char*)As + (wave * 4 + j) * 1024),
                16, 0, 0);
            aptr[j] += 32;
        }
#pragma unroll
        for (int j = 0; j < 2; ++j) {
            __builtin_amdgcn_global_load_lds(
                (const __attribute__((address_space(1))) void*)(bptr[j]),
                (__attribute__((address_space(3))) void*)((char*)Bs + (wave * 2 + j) * 1024),
                16, 0, 0);
            bptr[j] += 32;
        }
        __syncthreads();

        short8v bfr[4];
#pragma unroll
        for (int nf = 0; nf < 4; ++nf) {
            int n = wx * 64 + nf * 16 + c;
            bfr[nf] = *(const short8v*)(Bs + n * 32 + k8);
        }
#pragma unroll
        for (int mf = 0; mf < 4; ++mf) {
            int m = wy * 64 + mf * 16 + c;
            float4v lo = *(const float4v*)(As + m * 32 + k8);
            float4v hi = *(const float4v*)(As + m * 32 + k8 + 4);
            short8v afr = cvt_f32x8_bf16(lo, hi);
#pragma unroll
            for (int nf = 0; nf < 4; ++nf)
                acc[mf][nf] = __builtin_amdgcn_mfma_f32_16x16x32_bf16(
                    afr, bfr[nf], acc[mf][nf], 0, 0, 0);
        }
    }

    // Epilogue: tanh(acc + qproj) * v, reduce over h (columns), atomic into attn.
    const int b = tileR >> 4;   // 16 row-tiles per batch (2048/128)
    float vv[4], qp[4];
#pragma unroll
    for (int nf = 0; nf < 4; ++nf) {
        int h   = h0 + wx * 64 + nf * 16 + c;
        vv[nf] = vvec[h];
        qp[nf] = qproj[b * HH + h];
    }
    float rs[4][4];
#pragma unroll
    for (int mf = 0; mf < 4; ++mf)
#pragma unroll
        for (int r = 0; r < 4; ++r) rs[mf][r] = 0.0f;
#pragma unroll
    for (int mf = 0; mf < 4; ++mf)
#pragma unroll
        for (int nf = 0; nf < 4; ++nf)
#pragma unroll
            for (int r = 0; r < 4; ++r)
                rs[mf][r] += fast_tanh(acc[mf][nf][r] + qp[nf]) * vv[nf];

    // C/D layout: col = lane&15 (h), row = (lane>>4)*4 + reg (memory row).
    // Reduce the 16 columns held across lanes (xor over low 4 lane bits).
#pragma unroll
    for (int mf = 0; mf < 4; ++mf)
#pragma unroll
        for (int r = 0; r < 4; ++r) {
            float s = rs[mf][r];
            s += __shfl_xor(s, 1);
            s += __shfl_xor(s, 2);
            s += __shfl_xor(s, 4);
            s += __shfl_xor(s, 8);
            if (c == 0)
                atomicAdd(attn + (r0 + wy * 64 + mf * 16 + g * 4 + r), s);
        }
}

// ---------------------------------------------------------------- softmax over M
__global__ __launch_bounds__(256) void softmax_kernel(const float* __restrict__ attn,
                                                      float* __restrict__ wout) {
    const int b = blockIdx.x, tid = threadIdx.x;
    __shared__ float red[8];
    float a[8];
    float mx = -1e30f;
#pragma unroll
    for (int i = 0; i < 8; ++i) {
        a[i] = attn[b * MM + i * 256 + tid];
        mx = fmaxf(mx, a[i]);
    }
#pragma unroll
    for (int off = 1; off < 64; off <<= 1) mx = fmaxf(mx, __shfl_xor(mx, off));
    if ((tid & 63) == 0) red[tid >> 6] = mx;
    __syncthreads();
    mx = fmaxf(fmaxf(red[0], red[1]), fmaxf(red[2], red[3]));
    float s = 0.0f;
#pragma unroll
    for (int i = 0; i < 8; ++i) {
        a[i] = __builtin_amdgcn_exp2f((a[i] - mx) * 1.4426950408889634f);
        s += a[i];
    }
#pragma unroll
    for (int off = 1; off < 64; off <<= 1) s += __shfl_xor(s, off);
    if ((tid & 63) == 0) red[4 + (tid >> 6)] = s;
    __syncthreads();
    s = red[4] + red[5] + red[6] + red[7];
    float inv = 1.0f / s;
#pragma unroll
    for (int i = 0; i < 8; ++i) wout[b * MM + i * 256 + tid] = a[i] * inv;
}

// ---------------------------------------------------------------- weighted memory
// out2[b,d] = sum_m w[b,m] * memory[b,m,d]; m split x4, atomic accumulate.
__global__ __launch_bounds__(256) void wmem_kernel(const float* __restrict__ mem,
                                                   const float* __restrict__ w,
                                                   float* __restrict__ out2) {
    const int b  = blockIdx.z;
    const int d  = blockIdx.x * 256 + threadIdx.x;
    const int m0 = blockIdx.y * 512;
    __shared__ float wsh[512];
    for (int i = threadIdx.x; i < 512; i += 256) wsh[i] = w[b * MM + m0 + i];
    __syncthreads();
    const float* mp = mem + ((size_t)(b * MM + m0)) * DD + d;
    float acc = 0.0f;
#pragma unroll 8
    for (int m = 0; m < 512; ++m)
        acc = __builtin_fmaf(wsh[m], mp[(size_t)m * DD], acc);
    atomicAdd(out2 + b * DD + d, acc);
}

// ---------------------------------------------------------------- launcher
extern "C" void kernel_launch(void* const* d_in, const int* in_sizes, int n_in,
                              void* d_out, int out_size, void* d_ws, size_t ws_size,
                              hipStream_t stream) {
    const float* query  = (const float*)d_in[0];
    const float* memory = (const float*)d_in[1];
    const float* Wq     = (const float*)d_in[2];
    const float* bq     = (const float*)d_in[3];
    const float* Wm     = (const float*)d_in[4];
    const float* v      = (const float*)d_in[5];

    float* out      = (float*)d_out;
    float* wout     = out;                       // weights [64,1,2048]
    float* wmem_out = out + BSZ * MM;            // weighted_memory [64,1,1024]

    char*  ws    = (char*)d_ws;
    float* qproj = (float*)ws;                   // 256 KB
    float* attn  = (float*)(ws + 262144);        // 512 KB
    short* wmbf  = (short*)(ws + 786432);        // 2 MB  (total 2.75 MB of ws)

    hipMemsetAsync(attn, 0, (size_t)RR * sizeof(float), stream);
    hipMemsetAsync(d_out, 0, (size_t)out_size * sizeof(float), stream);

    cast_wm_kernel<<<HH * DD / (256 * 4), 256, 0, stream>>>(Wm, wmbf);
    qproj_kernel<<<dim3(HH / 256, BSZ), 256, 0, stream>>>(query, Wq, bq, qproj);
    gemm_attn_kernel<<<(RR / 128) * (HH / 128), 256, 0, stream>>>(memory, wmbf, qproj, v, attn);
    softmax_kernel<<<BSZ, 256, 0, stream>>>(attn, wout);
    wmem_kernel<<<dim3(DD / 256, 4, BSZ), 256, 0, stream>>>(memory, wout, wmem_out);
}